// Round 14
// baseline (2528.819 us; speedup 1.0000x reference)
//
#include <hip/hip_runtime.h>

// Two-layer tanh RNN, H=32, B=64, T=16384. Latency-bound sequential scan.
//
// Round-30: halve the bpermute broadcast via pair-split rows.
// Transport ranking R27(16bperm)=1838 < R29(hybrid)=1974 < R28(LDS)=2076
// => crossbar-only transport, fewer ops. New layout: lane pair (2r,2r+1)
// owns row r; lane m does half q=(m&1) (cols 16q..16q+15) of BOTH of its
// wave's matrices. Each lane needs only 8 state pairs -> 8 bpermutes
// (addr = 128*(m&1) + 16*j, per-lane base + imm offsets). Partial sums
// combine with one DPP pair_add per matrix; both lanes of a pair get the
// full row value -> state lives in PAIR layout (h[r] dup in lanes 2r,2r+1).
// Pack: quad_perm[2,3,0,1] + cvt_pkrtz at lanes 4p = pair p (bperm sources).
// Seeds carried by even lanes only (odd=0) so pair_add adds them once.
//  - wave A: w1=TSC*Whh0[r] half, w2=TSC*Wih1[r] half (u published scaled)
//  - wave B: w1=TSC*Whh1[r] half, w2=Wout half (raw; all pairs -> all
//    lanes hold out after pair_add)
// u-window ring/barriers/epilogues structurally as R27. stg deleted.

#define T_LEN 16384
#define B_SZ  64
#define NW    (T_LEN / 32)   // 512 windows
#define TSC   2.885390082f   // 2*log2(e)

#if __has_builtin(__builtin_amdgcn_exp2f)
#define EXP2(x) __builtin_amdgcn_exp2f(x)
#else
#define EXP2(x) exp2f(x)
#endif

typedef _Float16 h2 __attribute__((ext_vector_type(2)));

__device__ __forceinline__ float rl(float v, int lane) {
  return __int_as_float(__builtin_amdgcn_readlane(__float_as_int(v), lane));
}

// Crossbar broadcast: lane pulls src register of lane (byteaddr>>2).
__device__ __forceinline__ h2 bperm_h2(int byteaddr, h2 v) {
  int o = __builtin_amdgcn_ds_bpermute(byteaddr, __builtin_bit_cast(int, v));
  return __builtin_bit_cast(h2, o);
}

// quad_perm([1,0,3,2]): swap within lane pairs.
__device__ __forceinline__ float pair_add(float v) {
  int t = __builtin_amdgcn_update_dpp(0, __float_as_int(v), 0xB1, 0xF, 0xF, true);
  return v + __int_as_float(t);
}

// quad_perm([2,3,0,1]): lane 4p sees lane 4p+2's value.
__device__ __forceinline__ float quad2_swap(float v) {
  int t = __builtin_amdgcn_update_dpp(0, __float_as_int(v), 0x4E, 0xF, 0xF, true);
  return __int_as_float(t);
}

// tanh with 2*log2(e) pre-folded: tanh = 1 - 2/(2^v+1). 4-dep chain.
__device__ __forceinline__ float tanh_pre(float v) {
  float e = EXP2(v);
  return fmaf(-2.f, __builtin_amdgcn_rcpf(e + 1.f), 1.f);
}

#if __has_builtin(__builtin_amdgcn_fdot2)
#define FDOT2(a, b, c) __builtin_amdgcn_fdot2((a), (b), (c), false)
#else
#define FDOT2(a, b, c) \
  fmaf((float)(a).x, (float)(b).x, fmaf((float)(a).y, (float)(b).y, (c)))
#endif

// Pack for pair layout: at lane 4p, own h = h[2p], quad2_swap = h[2p+1]
// (lane 4p+2's value). cvt_pkrtz -> pair p. Other lanes pack unread junk.
__device__ __forceinline__ h2 pack_pair(float hcur) {
  float hsw = quad2_swap(hcur);
#if __has_builtin(__builtin_amdgcn_cvt_pkrtz)
  return __builtin_bit_cast(h2, __builtin_amdgcn_cvt_pkrtz(hcur, hsw));
#else
  h2 p; p.x = (_Float16)hcur; p.y = (_Float16)hsw; return p;
#endif
}

// Half-row dot: 8 dot2 over this lane's 16 columns, 4 accs + tree.
__device__ __forceinline__ float dot16h(const h2* w, const h2* hb, float seed) {
  float a0 = seed, a1 = 0.f, a2 = 0.f, a3 = 0.f;
#pragma unroll
  for (int j = 0; j < 2; ++j) {
    a0 = FDOT2(w[4 * j + 0], hb[4 * j + 0], a0);
    a1 = FDOT2(w[4 * j + 1], hb[4 * j + 1], a1);
    a2 = FDOT2(w[4 * j + 2], hb[4 * j + 2], a2);
    a3 = FDOT2(w[4 * j + 3], hb[4 * j + 3], a3);
  }
  return (a0 + a1) + (a2 + a3);
}

// 8-bpermute broadcast of this lane's half (pairs 8q..8q+7).
#define BCAST8(hb, hpk)                                        \
  _Pragma("unroll")                                            \
  for (int j_ = 0; j_ < 8; ++j_)                               \
    (hb)[j_] = bperm_h2(abase + 16 * j_, (hpk));

__global__ __launch_bounds__(128, 1) void rnn2_kernel(
    const float* __restrict__ x,    const float* __restrict__ hs,
    const float* __restrict__ Wih0, const float* __restrict__ Whh0,
    const float* __restrict__ bih0, const float* __restrict__ bhh0,
    const float* __restrict__ Wih1, const float* __restrict__ Whh1,
    const float* __restrict__ bih1, const float* __restrict__ bhh1,
    const float* __restrict__ Wout, const float* __restrict__ bout,
    float* __restrict__ out)
{
  __shared__ __align__(16) float uwin[2][1024];   // A->B; slot t2*32 + row
  __shared__ __align__(16) float scratch[1024];   // sink (never read)

  const int  tid = (int)threadIdx.x;
  const int  wv  = tid >> 6;            // 0 = wave A (h0), 1 = wave B (h1)
  const int  m   = tid & 63;
  const int  r   = m >> 1;              // row owned by this lane pair
  const bool q0  = !(m & 1);            // even lane = cols 0-15 + seeds
  const int  b   = (int)blockIdx.x;

  // Per-lane HALF rows (16 floats = 8 f16 pairs), TSC pre-folded where the
  // result feeds tanh (or the published u):
  //  A: w1 = TSC*Whh0[r][16q..], w2 = TSC*Wih1[r][16q..]
  //  B: w1 = TSC*Whh1[r][16q..], w2 = Wout[16q..] (raw)
  const int  qo  = (m & 1) * 16;
  const float* pw1 = (wv == 0) ? (Whh0 + r * 32 + qo) : (Whh1 + r * 32 + qo);
  const float* pw2 = (wv == 0) ? (Wih1 + r * 32 + qo) : (Wout + qo);
  const float s2 = (wv == 0) ? TSC : 1.f;
  h2 w1[8], w2[8];
#pragma unroll
  for (int k = 0; k < 4; ++k) {
    float4 qa = ((const float4*)pw1)[k];
    w1[2 * k].x     = (_Float16)(qa.x * TSC);
    w1[2 * k].y     = (_Float16)(qa.y * TSC);
    w1[2 * k + 1].x = (_Float16)(qa.z * TSC);
    w1[2 * k + 1].y = (_Float16)(qa.w * TSC);
    float4 qb = ((const float4*)pw2)[k];
    w2[2 * k].x     = (_Float16)(qb.x * s2);
    w2[2 * k].y     = (_Float16)(qb.y * s2);
    w2[2 * k + 1].x = (_Float16)(qb.z * s2);
    w2[2 * k + 1].y = (_Float16)(qb.w * s2);
  }

  // Seeds live in EVEN lanes only (odd lanes 0) so pair_add counts them once.
  float xw = 0.f, b1c = 0.f, b2c = 0.f;
  if (wv == 0 && q0) {
    xw  = TSC * Wih0[r];
    b1c = TSC * (bih0[r] + bhh0[r]);
    b2c = TSC * (bih1[r] + bhh1[r]);
  }
  const float bo = bout[0];

  // State in PAIR layout: h[r] duplicated in lanes 2r, 2r+1.
  float hcur = (wv == 0) ? hs[b * 32 + r] : hs[2048 + b * 32 + r];

  // bpermute base: even lanes pull pairs 0-7 (lanes 0,4,..28 -> bytes 0..112),
  // odd lanes pairs 8-15 (lanes 32,36,..60 -> bytes 128..240).
  const int abase = 128 * (m & 1);

  // u publish: even lane of pair r -> uwin row r; odd lanes -> sink.
  float* up0 = q0 ? &uwin[0][r] : &scratch[m];
  float* up1 = q0 ? &uwin[1][r] : &scratch[m];

  const float* xb   = x + (size_t)b * T_LEN;
  float*       outp = out + (size_t)b * T_LEN;       // outs[b*T + t]
  float*       hf   = out + (size_t)B_SZ * T_LEN;    // h_final [2,B,H]

  float obuf = 0.f;
  float xcur = 0.f;
  if (wv == 0) xcur = xb[m];            // window 0 chunk (lanes 0..31 used)

  for (int wdx = 0; wdx <= NW; ++wdx) {
    if (wv == 0) {
      if (wdx < NW) {
        // Prefetch next window's x chunk; consumed 32 steps from now.
        float xnext = 0.f;
        if (wdx + 1 < NW) {
          int xi = 32 * (wdx + 1) + m; if (xi > T_LEN - 1) xi = T_LEN - 1;
          xnext = xb[xi];
        }
        float* up = (wdx & 1) ? up1 : up0;
#pragma unroll 8
        for (int t2 = 0; t2 < 32; ++t2) {
          h2 hpk = pack_pair(hcur);         // h0n(t-1) pair p at lane 4p
          h2 hb[8];
          BCAST8(hb, hpk);                  // 8 bpermutes (half state)
          float xv    = rl(xcur, t2);       // x(t)   (off-chain)
          float seed1 = fmaf(xv, xw, b1c);  // even: TSC*(x*W+b0); odd: 0
          float acc1 = dot16h(w1, hb, seed1);
          float acc2 = dot16h(w2, hb, b2c);
          float a1f = pair_add(acc1);       // full Whh0 row dot (+seed)
          float a2f = pair_add(acc2);       // full u(t-1) = TSC*(b1+Wih1.h0)
          up[t2 * 32] = a2f;                // even publishes u; odd -> sink
          hcur = tanh_pre(a1f);             // h0n(t) in both pair lanes
        }
        xcur = xnext;
      }
    } else {
      if (wdx >= 1) {
        const int wb = wdx - 1;             // steps t = 32*wb-1 .. 32*wb+30
        const float* ub = &uwin[wb & 1][r];
        float uval = ub[0];                 // TSC*u(32*wb-1)
#pragma unroll 8
        for (int t2 = 0; t2 < 32; ++t2) {
          const int t = 32 * wb - 1 + t2;
          h2 hpk = pack_pair(hcur);         // h1n(t-1) pairs
          h2 hb[8];
          BCAST8(hb, hpk);                  // 8 bpermutes
          float seed1 = q0 ? uval : 0.f;    // u seed once (even lane)
          float acc1 = dot16h(w1, hb, seed1);
          float acc2 = dot16h(w2, hb, 0.f);
          float unext = ub[((t2 + 1) & 31) * 32];  // pipelined u-read
          float a1f = pair_add(acc1);       // u + TSC*Whh1.h1 (full)
          float a2f = pair_add(acc2);       // out(t-1)-bo (all lanes)
          float h1n = tanh_pre(a1f);
          obuf = (m == t2) ? a2f : obuf;    // lane t2 keeps out(32wb-2+t2)
          if (t >= 0) hcur = h1n;           // uniform guard (skips wb=0,t2=0)
          uval = unext;
        }
        const int idx = 32 * wb - 2 + m;    // lane m<32 holds out(idx)
        if (m < 32 && idx >= 0) outp[idx] = obuf + bo;   // coalesced store
      }
    }
    __syncthreads();   // window handoff (uwin parity swap)
  }

  // Epilogue 1 (wave A): publish TSC*u(T-1); store h_final L0.
  if (wv == 0) {
    h2 hpk = pack_pair(hcur);               // h0n(T-1)
    h2 hb[8];
    BCAST8(hb, hpk);
    float acc2 = dot16h(w2, hb, b2c);
    float a2f = pair_add(acc2);             // TSC*(b1 + Wih1.h0n(T-1))
    if (q0) { uwin[0][r] = a2f; hf[b * 32 + r] = hcur; }
  }
  __syncthreads();

  // Epilogue 2 (wave B): h1n(T-1), out(T-2), out(T-1), h_final L1.
  if (wv == 1) {
    float uT = uwin[0][r];                  // TSC*u(T-1)
    h2 hpk = pack_pair(hcur);               // h1n(T-2)
    h2 hb[8];
    BCAST8(hb, hpk);
    float acc1 = dot16h(w1, hb, q0 ? uT : 0.f);
    float acc2 = dot16h(w2, hb, 0.f);
    float a1f = pair_add(acc1);
    float a2f = pair_add(acc2);             // out(T-2)-bo
    if (m == 0) outp[T_LEN - 2] = a2f + bo;
    float h1T = tanh_pre(a1f);              // h1n(T-1), both pair lanes
    h2 hpk2 = pack_pair(h1T);
    h2 hb2[8];
    BCAST8(hb2, hpk2);
    float acc2b = dot16h(w2, hb2, 0.f);
    float a2bf = pair_add(acc2b);           // out(T-1)-bo
    if (m == 0) outp[T_LEN - 1] = a2bf + bo;
    if (q0) hf[2048 + b * 32 + r] = h1T;    // h_final layer 1
  }
}

extern "C" void kernel_launch(void* const* d_in, const int* in_sizes, int n_in,
                              void* d_out, int out_size, void* d_ws, size_t ws_size,
                              hipStream_t stream) {
  rnn2_kernel<<<dim3(B_SZ), dim3(128), 0, stream>>>(
      (const float*)d_in[0],  (const float*)d_in[1],  (const float*)d_in[2],
      (const float*)d_in[3],  (const float*)d_in[4],  (const float*)d_in[5],
      (const float*)d_in[6],  (const float*)d_in[7],  (const float*)d_in[8],
      (const float*)d_in[9],  (const float*)d_in[10], (const float*)d_in[11],
      (float*)d_out);
}

// Round 15
// 1836.449 us; speedup vs baseline: 1.3770x; 1.3770x over previous
//
#include <hip/hip_runtime.h>

// Two-layer tanh RNN, H=32, B=64, T=16384. Latency-bound sequential scan.
//
// Round-31: R27 (1838 us green, absmax 3.906e-3) with the 16-op broadcast
// SPLIT ACROSS PIPES: pairs 0-7 via v_readlane (VALU), pairs 8-15 via
// uniform-address ds_bpermute (DS pipe), interleaved in program order.
// R30's lesson (35.6M bank conflicts): bpermute must be UNIFORM-address.
// Evidence: 16 ops on VALU (R18) = 16 ops on DS (R26) = ~128 cyc; a wave
// issues in order ~1/cyc to DIFFERENT pipes, so 8+8 interleaved should
// let both pipes work concurrently -> transport ~64 cyc. Same source
// lanes, same bits, same dot order as R27 => absmax exactly 0.00390625.
// All R27 cuts retained: TSC pre-folded weights/seeds (4-dep tanh), uval
// folded into wave-B seed, cvt_pkrtz pack, unroll 8.

#define T_LEN 16384
#define B_SZ  64
#define NW    (T_LEN / 32)   // 512 windows
#define TSC   2.885390082f   // 2*log2(e)

#if __has_builtin(__builtin_amdgcn_exp2f)
#define EXP2(x) __builtin_amdgcn_exp2f(x)
#else
#define EXP2(x) exp2f(x)
#endif

typedef _Float16 h2 __attribute__((ext_vector_type(2)));

__device__ __forceinline__ float rl(float v, int lane) {
  return __int_as_float(__builtin_amdgcn_readlane(__float_as_int(v), lane));
}

__device__ __forceinline__ h2 rl_h2(h2 v, int lane) {
  int o = __builtin_amdgcn_readlane(__builtin_bit_cast(int, v), lane);
  return __builtin_bit_cast(h2, o);
}

// Wave-uniform broadcast via the LDS crossbar (conflict-free mode): every
// lane pulls the pack register of lane (byteaddr>>2), byteaddr uniform.
__device__ __forceinline__ h2 bperm_h2(int byteaddr, h2 v) {
  int o = __builtin_amdgcn_ds_bpermute(byteaddr, __builtin_bit_cast(int, v));
  return __builtin_bit_cast(h2, o);
}

// quad_perm([1,0,3,2]): each lane sees its pair-neighbor's value.
__device__ __forceinline__ float pair_swap(float v) {
  int t = __builtin_amdgcn_update_dpp(0, __float_as_int(v), 0xB1, 0xF, 0xF, true);
  return __int_as_float(t);
}

// tanh with the 2*log2(e) scale PRE-FOLDED into the argument:
// tanh = 1 - 2/(2^v + 1), v = 2*log2(e)*x. 4-dep chain (mul removed).
__device__ __forceinline__ float tanh_pre(float v) {
  float e = EXP2(v);
  return fmaf(-2.f, __builtin_amdgcn_rcpf(e + 1.f), 1.f);
}

#if __has_builtin(__builtin_amdgcn_fdot2)
#define FDOT2(a, b, c) __builtin_amdgcn_fdot2((a), (b), (c), false)
#else
#define FDOT2(a, b, c) \
  fmaf((float)(a).x, (float)(b).x, fmaf((float)(a).y, (float)(b).y, (c)))
#endif

// Pack this lane's state with its pair-neighbor: even lane 2j ends with
// (h[2j], h[2j+1]). DPP on f32 first, then ONE packed convert (RTZ).
__device__ __forceinline__ h2 pack_state(float hcur) {
  float hsw = pair_swap(hcur);
#if __has_builtin(__builtin_amdgcn_cvt_pkrtz)
  return __builtin_bit_cast(h2, __builtin_amdgcn_cvt_pkrtz(hcur, hsw));
#else
  h2 p; p.x = (_Float16)hcur; p.y = (_Float16)hsw; return p;
#endif
}

// Dual-pipe broadcast: pair j (source lane 2j). j=0..7 via readlane
// (VALU), j=8..15 via uniform bpermute (DS), interleaved so both pipes
// fill concurrently.
#define BCASTMIX(dst, src_pk)                                  \
  _Pragma("unroll")                                            \
  for (int j_ = 0; j_ < 8; ++j_) {                             \
    (dst)[j_]     = rl_h2((src_pk), 2 * j_);                   \
    (dst)[j_ + 8] = bperm_h2(64 + 8 * j_, (src_pk));           \
  }

// 32-term dot via 16 dot2, 4 accumulators (depth 4) + 2-level tree.
__device__ __forceinline__ float dot32h(const h2* w, const h2* hb, float seed) {
  float a0 = seed, a1 = 0.f, a2 = 0.f, a3 = 0.f;
#pragma unroll
  for (int j = 0; j < 4; ++j) {
    a0 = FDOT2(w[4 * j + 0], hb[4 * j + 0], a0);
    a1 = FDOT2(w[4 * j + 1], hb[4 * j + 1], a1);
    a2 = FDOT2(w[4 * j + 2], hb[4 * j + 2], a2);
    a3 = FDOT2(w[4 * j + 3], hb[4 * j + 3], a3);
  }
  return (a0 + a1) + (a2 + a3);
}

__global__ __launch_bounds__(128, 1) void rnn2_kernel(
    const float* __restrict__ x,    const float* __restrict__ hs,
    const float* __restrict__ Wih0, const float* __restrict__ Whh0,
    const float* __restrict__ bih0, const float* __restrict__ bhh0,
    const float* __restrict__ Wih1, const float* __restrict__ Whh1,
    const float* __restrict__ bih1, const float* __restrict__ bhh1,
    const float* __restrict__ Wout, const float* __restrict__ bout,
    float* __restrict__ out)
{
  __shared__ __align__(16) float uwin[2][1024];   // A->B; slot t2*32 + row
  __shared__ __align__(16) float scratch[1024];   // sink for lo-lane publishes

  const int  tid = (int)threadIdx.x;
  const int  wv  = tid >> 6;            // 0 = wave A (h0), 1 = wave B (h1)
  const int  m   = tid & 63;
  const int  r   = m & 31;              // row owned by this lane
  const bool hi  = (m >= 32);           // secondary-matrix half
  const int  b   = (int)blockIdx.x;

  // Per-lane full 32-float row, packed to 16 f16 pairs, with the tanh
  // input scale TSC pre-folded where the dot feeds tanh (or the published
  // u, which wave B consumes as a pre-scaled tanh seed):
  //  A: lo = TSC*Whh0[r], hi = TSC*Wih1[r]   (published u = TSC*u_raw)
  //  B: lo = TSC*Whh1[r], hi = Wout (raw; feeds out, not tanh)
  const float* pw = (wv == 0) ? (hi ? (Wih1 + r * 32) : (Whh0 + r * 32))
                              : (hi ? Wout : (Whh1 + r * 32));
  const float wsc = (wv == 0) ? TSC : (hi ? 1.f : TSC);
  h2 w[16];
#pragma unroll
  for (int k = 0; k < 8; ++k) {
    float4 q = ((const float4*)pw)[k];
    w[2 * k].x     = (_Float16)(q.x * wsc);
    w[2 * k].y     = (_Float16)(q.y * wsc);
    w[2 * k + 1].x = (_Float16)(q.z * wsc);
    w[2 * k + 1].y = (_Float16)(q.w * wsc);
  }

  float xw = 0.f, binv = 0.f;
  if (wv == 0) {
    if (hi) binv = TSC * (bih1[r] + bhh1[r]);    // u seed: TSC*b1
    else  { binv = TSC * (bih0[r] + bhh0[r]); xw = TSC * Wih0[r]; }
  }
  const float bo = bout[0];

  // State register: lane k (k<32) holds h[k] in f32 (raw, unscaled). Hi
  // lanes carry garbage copies; pack_state/BCASTMIX read even lanes 0..30.
  float hcur = (wv == 0) ? hs[b * 32 + r] : hs[2048 + b * 32 + r];

  // Wave A publish pointers: hi lanes -> uwin row r, lo lanes -> scratch.
  float* up0 = hi ? &uwin[0][r] : &scratch[r];
  float* up1 = hi ? &uwin[1][r] : &scratch[r];

  const float* xb   = x + (size_t)b * T_LEN;
  float*       outp = out + (size_t)b * T_LEN;       // outs[b*T + t]
  float*       hf   = out + (size_t)B_SZ * T_LEN;    // h_final [2,B,H]

  float obuf = 0.f;
  float xcur = 0.f;
  if (wv == 0) xcur = xb[m];            // window 0 chunk (lanes 0..31 used)

  for (int wdx = 0; wdx <= NW; ++wdx) {
    if (wv == 0) {
      if (wdx < NW) {
        // Prefetch next window's x chunk; consumed 32 steps from now.
        float xnext = 0.f;
        if (wdx + 1 < NW) {
          int xi = 32 * (wdx + 1) + m; if (xi > T_LEN - 1) xi = T_LEN - 1;
          xnext = xb[xi];
        }
        float* up = (wdx & 1) ? up1 : up0;
#pragma unroll 8
        for (int t2 = 0; t2 < 32; ++t2) {
          h2 hpk = pack_state(hcur);        // h0n(t-1) packed pairs
          h2 hb[16];
          BCASTMIX(hb, hpk);                // 8 readlane + 8 bperm, 2 pipes
          float xv   = rl(xcur, t2);        // x(t)   (off-chain)
          float seed = fmaf(xv, xw, binv);  // lo: TSC*(x*W+b0); hi: TSC*b1
          float acc  = dot32h(w, hb, seed); // lo: tanh arg; hi: TSC*u(t-1)
          up[t2 * 32] = acc;                // hi publishes u; lo -> scratch
          hcur = tanh_pre(acc);             // lo lanes: h0n(t)
        }
        xcur = xnext;
      }
    } else {
      if (wdx >= 1) {
        const int wb = wdx - 1;             // steps t = 32*wb-1 .. 32*wb+30
        const float* ub = &uwin[wb & 1][r];
        float uval = ub[0];                 // TSC*u(32*wb-1)
#pragma unroll 8
        for (int t2 = 0; t2 < 32; ++t2) {
          const int t = 32 * wb - 1 + t2;
          h2 hpk = pack_state(hcur);        // h1n(t-1) packed pairs
          h2 hb[16];
          BCASTMIX(hb, hpk);                // 8 readlane + 8 bperm, 2 pipes
          float sB  = hi ? 0.f : uval;      // uval folded into seed
          float acc = dot32h(w, hb, sB);    // lo: tanh arg; hi: out(t-1)-bo
          float unext = ub[((t2 + 1) & 31) * 32];  // pipelined u-read
          float h1n = tanh_pre(acc);
          obuf = (m == 32 + t2) ? acc : obuf;      // hi lane t2: out(t-1)-bo
          if (t >= 0) hcur = h1n;           // uniform guard (skips wb=0,t2=0)
          uval = unext;
        }
        const int idx = 32 * wb - 2 + r;    // hi lane 32+k holds out(32wb-2+k)
        if (hi && idx >= 0) outp[idx] = obuf + bo;   // coalesced store
      }
    }
    __syncthreads();   // window handoff (uwin parity swap)
  }

  // Epilogue 1 (wave A): publish TSC*u(T-1) from h0n(T-1); h_final L0.
  if (wv == 0) {
    h2 hpk = pack_state(hcur);              // h0n(T-1)
    h2 hb[16];
    BCASTMIX(hb, hpk);
    float acc = dot32h(w, hb, binv);        // hi: TSC*(b1 + Wih1.h0n(T-1))
    if (hi) uwin[0][r] = acc;
    else    hf[b * 32 + r] = hcur;          // h_final layer 0 (full f32)
  }
  __syncthreads();

  // Epilogue 2 (wave B): h1n(T-1), out(T-2), out(T-1), h_final L1.
  if (wv == 1) {
    float uT = uwin[0][r];                  // TSC*u(T-1)
    h2 hpk = pack_state(hcur);              // h1n(T-2)
    h2 hb[16];
    BCASTMIX(hb, hpk);
    float acc = dot32h(w, hb, hi ? 0.f : uT);
    if (m == 32) outp[T_LEN - 2] = acc + bo;      // Wout . h1n(T-2) (raw hi)
    float h1T = tanh_pre(acc);              // valid in lo lanes
    h2 hpk2 = pack_state(h1T);              // h1n(T-1)
    h2 hb2[16];
    BCASTMIX(hb2, hpk2);
    float acc2 = dot32h(w, hb2, 0.f);
    if (m == 32) outp[T_LEN - 1] = acc2 + bo;     // Wout . h1n(T-1)
    if (!hi) hf[2048 + b * 32 + r] = h1T;   // h_final layer 1 (full f32)
  }
}

extern "C" void kernel_launch(void* const* d_in, const int* in_sizes, int n_in,
                              void* d_out, int out_size, void* d_ws, size_t ws_size,
                              hipStream_t stream) {
  rnn2_kernel<<<dim3(B_SZ), dim3(128), 0, stream>>>(
      (const float*)d_in[0],  (const float*)d_in[1],  (const float*)d_in[2],
      (const float*)d_in[3],  (const float*)d_in[4],  (const float*)d_in[5],
      (const float*)d_in[6],  (const float*)d_in[7],  (const float*)d_in[8],
      (const float*)d_in[9],  (const float*)d_in[10], (const float*)d_in[11],
      (float*)d_out);
}